// Round 1
// baseline (816.166 us; speedup 1.0000x reference)
//
#include <hip/hip_runtime.h>
#include <hip/hip_bf16.h>
#include <math.h>

#define N_NODES 50000
#define N_EDGES 800000
#define F_IN    128
#define HID     64
#define HEADS   4
#define NCLS    16
#define NEG_SLOPE 0.2f

static __device__ __forceinline__ float lrelu(float x) {
    return x >= 0.f ? x : NEG_SLOPE * x;
}

// ---------------- CSR build ----------------
__global__ void k_hist(const int* __restrict__ dst, int* __restrict__ counts, int e) {
    int i = blockIdx.x * blockDim.x + threadIdx.x;
    if (i < e) atomicAdd(&counts[dst[i]], 1);
}

__global__ void k_scan(const int* __restrict__ counts, int* __restrict__ rowptr, int n) {
    __shared__ int buf[1024];
    __shared__ int carry;
    if (threadIdx.x == 0) carry = 0;
    __syncthreads();
    for (int base = 0; base < n; base += 1024) {
        int i = base + (int)threadIdx.x;
        int v = (i < n) ? counts[i] : 0;
        buf[threadIdx.x] = v;
        __syncthreads();
        for (int off = 1; off < 1024; off <<= 1) {
            int t = (threadIdx.x >= (unsigned)off) ? buf[threadIdx.x - off] : 0;
            __syncthreads();
            buf[threadIdx.x] += t;
            __syncthreads();
        }
        int incl = buf[threadIdx.x];
        int myout = carry + incl - v;   // exclusive
        __syncthreads();
        if (threadIdx.x == 1023) carry += incl;
        __syncthreads();
        if (i < n) rowptr[i] = myout;
    }
    if (threadIdx.x == 0) rowptr[n] = carry;
}

__global__ void k_scatter(const int* __restrict__ src, const int* __restrict__ dst,
                          const int* __restrict__ rowptr, int* __restrict__ cursor,
                          int* __restrict__ col, int e) {
    int i = blockIdx.x * blockDim.x + threadIdx.x;
    if (i < e) {
        int d = dst[i];
        int pos = rowptr[d] + atomicAdd(&cursor[d], 1);
        col[pos] = src[i];
    }
}

// ---------------- GEMM: C[M,N] = A[M,K] @ B[K,N], N multiple of 64 ----------------
__global__ __launch_bounds__(256) void k_gemm(const float* __restrict__ A,
                                              const float* __restrict__ B,
                                              float* __restrict__ C,
                                              int M, int K, int N) {
    const int BK = 16;
    __shared__ float As[64][BK + 1];
    __shared__ float Bs[BK][64];
    int bx = blockIdx.x;            // col block
    int by = blockIdx.y;            // row block
    int tx = threadIdx.x & 15;
    int ty = threadIdx.x >> 4;
    int row0 = by * 64, col0 = bx * 64;
    float acc[4][4] = {};
    for (int k0 = 0; k0 < K; k0 += BK) {
        // A tile: 64 x 16 = 1024 elems, 4 per thread
        #pragma unroll
        for (int j = 0; j < 4; j++) {
            int idx = threadIdx.x + j * 256;
            int r = idx >> 4, c = idx & 15;
            int gr = row0 + r;
            As[r][c] = (gr < M) ? A[(size_t)gr * K + k0 + c] : 0.f;
        }
        // B tile: 16 x 64 = 1024 elems
        #pragma unroll
        for (int j = 0; j < 4; j++) {
            int idx = threadIdx.x + j * 256;
            int r = idx >> 6, c = idx & 63;
            Bs[r][c] = B[(size_t)(k0 + r) * N + col0 + c];
        }
        __syncthreads();
        #pragma unroll
        for (int kk = 0; kk < BK; kk++) {
            float a[4], b[4];
            #pragma unroll
            for (int i = 0; i < 4; i++) a[i] = As[ty * 4 + i][kk];
            #pragma unroll
            for (int j = 0; j < 4; j++) b[j] = Bs[kk][tx * 4 + j];
            #pragma unroll
            for (int i = 0; i < 4; i++)
                #pragma unroll
                for (int j = 0; j < 4; j++) acc[i][j] += a[i] * b[j];
        }
        __syncthreads();
    }
    #pragma unroll
    for (int i = 0; i < 4; i++) {
        int gr = row0 + ty * 4 + i;
        if (gr < M) {
            #pragma unroll
            for (int j = 0; j < 4; j++)
                C[(size_t)gr * N + col0 + tx * 4 + j] = acc[i][j];
        }
    }
}

// ---------------- attention scores s_src/s_dst, layers 1&2 (H=4, D=64) ----------------
__global__ void k_scores(const float* __restrict__ h, const float* __restrict__ a_src,
                         const float* __restrict__ a_dst, float* __restrict__ s_src,
                         float* __restrict__ s_dst, int n) {
    int wave = (blockIdx.x * blockDim.x + threadIdx.x) >> 6;
    int lane = threadIdx.x & 63;
    if (wave >= n) return;
    float4 hv  = *(const float4*)(h + (size_t)wave * 256 + lane * 4);
    float4 av1 = *(const float4*)(a_src + lane * 4);  // flat [H*D] matches feature layout
    float4 av2 = *(const float4*)(a_dst + lane * 4);
    float ps = hv.x * av1.x + hv.y * av1.y + hv.z * av1.z + hv.w * av1.w;
    float pd = hv.x * av2.x + hv.y * av2.y + hv.z * av2.z + hv.w * av2.w;
    #pragma unroll
    for (int off = 1; off < 16; off <<= 1) {
        ps += __shfl_xor(ps, off);
        pd += __shfl_xor(pd, off);
    }
    if ((lane & 15) == 0) {
        int head = lane >> 4;
        s_src[wave * 4 + head] = ps;
        s_dst[wave * 4 + head] = pd;
    }
}

// ---------------- fused segment-softmax + aggregation, layers 1&2 ----------------
__global__ void k_aggregate(const float* __restrict__ h, const int* __restrict__ rowptr,
                            const int* __restrict__ col, const float* __restrict__ s_src,
                            const float* __restrict__ s_dst, const float* __restrict__ bias,
                            float* __restrict__ out, int n) {
    int wave = (blockIdx.x * blockDim.x + threadIdx.x) >> 6;
    int lane = threadIdx.x & 63;
    if (wave >= n) return;
    int head = lane >> 4;
    int f0 = lane * 4;
    float sd = s_dst[wave * 4 + head];
    float sc_self = lrelu(s_src[wave * 4 + head] + sd);
    int rs = rowptr[wave], re = rowptr[wave + 1];
    // pass 1: max
    float m = sc_self;
    for (int i = rs; i < re; i++) {
        float sc = lrelu(s_src[col[i] * 4 + head] + sd);
        m = fmaxf(m, sc);
    }
    // pass 2: exp-sum + weighted feature accumulation
    float z = 0.f;
    float a0 = 0.f, a1 = 0.f, a2 = 0.f, a3 = 0.f;
    {
        float p = __expf(sc_self - m);
        z += p;
        float4 hv = *(const float4*)(h + (size_t)wave * 256 + f0);
        a0 += p * hv.x; a1 += p * hv.y; a2 += p * hv.z; a3 += p * hv.w;
    }
    for (int i = rs; i < re; i++) {
        int s = col[i];
        float sc = lrelu(s_src[s * 4 + head] + sd);
        float p = __expf(sc - m);
        z += p;
        float4 hv = *(const float4*)(h + (size_t)s * 256 + f0);
        a0 += p * hv.x; a1 += p * hv.y; a2 += p * hv.z; a3 += p * hv.w;
    }
    float inv = 1.f / z;
    float4 bv = *(const float4*)(bias + f0);
    float o0 = a0 * inv + bv.x;
    float o1 = a1 * inv + bv.y;
    float o2 = a2 * inv + bv.z;
    float o3 = a3 * inv + bv.w;
    // ELU
    o0 = o0 > 0.f ? o0 : expm1f(o0);
    o1 = o1 > 0.f ? o1 : expm1f(o1);
    o2 = o2 > 0.f ? o2 : expm1f(o2);
    o3 = o3 > 0.f ? o3 : expm1f(o3);
    float4 ov = {o0, o1, o2, o3};
    *(float4*)(out + (size_t)wave * 256 + f0) = ov;
}

// ---------------- layer 3: GEMM [M,256]@[256,16] ----------------
__global__ __launch_bounds__(256) void k_gemm3(const float* __restrict__ A,
                                               const float* __restrict__ B,
                                               float* __restrict__ C, int M, int K) {
    __shared__ float Bs[256 * 16];
    for (int i = threadIdx.x; i < K * 16; i += blockDim.x) Bs[i] = B[i];
    __syncthreads();
    int tx = threadIdx.x & 15;   // col
    int ty = threadIdx.x >> 4;   // row in block
    int row = blockIdx.x * 16 + ty;
    if (row >= M) return;
    float acc = 0.f;
    for (int k = 0; k < K; k++) acc += A[(size_t)row * K + k] * Bs[k * 16 + tx];
    C[(size_t)row * 16 + tx] = acc;
}

// ---------------- layer 3 scores (H=1, D=16) ----------------
__global__ void k_scores3(const float* __restrict__ h3, const float* __restrict__ a_src,
                          const float* __restrict__ a_dst, float* __restrict__ s_src,
                          float* __restrict__ s_dst, int n) {
    int i = blockIdx.x * blockDim.x + threadIdx.x;
    if (i >= n) return;
    float ps = 0.f, pd = 0.f;
    #pragma unroll
    for (int c = 0; c < 16; c++) {
        float v = h3[(size_t)i * 16 + c];
        ps += v * a_src[c];
        pd += v * a_dst[c];
    }
    s_src[i] = ps;
    s_dst[i] = pd;
}

// ---------------- layer 3 aggregation + bias + log_softmax ----------------
__global__ void k_agg3(const float* __restrict__ h3, const int* __restrict__ rowptr,
                       const int* __restrict__ col, const float* __restrict__ s_src,
                       const float* __restrict__ s_dst, const float* __restrict__ b3,
                       float* __restrict__ outp, int n) {
    int wave = (blockIdx.x * blockDim.x + threadIdx.x) >> 6;
    int lane = threadIdx.x & 63;
    if (wave >= n) return;
    float sd = s_dst[wave];
    float sc_self = lrelu(s_src[wave] + sd);
    int rs = rowptr[wave], re = rowptr[wave + 1];
    float m = sc_self;
    for (int i = rs; i < re; i++) m = fmaxf(m, lrelu(s_src[col[i]] + sd));
    float z = 0.f, acc = 0.f;
    {
        float p = __expf(sc_self - m);
        z += p;
        if (lane < 16) acc += p * h3[(size_t)wave * 16 + lane];
    }
    for (int i = rs; i < re; i++) {
        int s = col[i];
        float p = __expf(lrelu(s_src[s] + sd) - m);
        z += p;
        if (lane < 16) acc += p * h3[(size_t)s * 16 + lane];
    }
    if (lane < 16) {
        float v = acc / z + b3[lane];
        float mm = v;
        #pragma unroll
        for (int off = 1; off < 16; off <<= 1) mm = fmaxf(mm, __shfl_xor(mm, off));
        float se = __expf(v - mm);
        #pragma unroll
        for (int off = 1; off < 16; off <<= 1) se += __shfl_xor(se, off);
        outp[(size_t)wave * 16 + lane] = v - mm - logf(se);
    }
}

extern "C" void kernel_launch(void* const* d_in, const int* in_sizes, int n_in,
                              void* d_out, int out_size, void* d_ws, size_t ws_size,
                              hipStream_t stream) {
    const float* x      = (const float*)d_in[0];
    const int*   ei     = (const int*)d_in[1];
    const float* W1     = (const float*)d_in[2];
    const float* a1_src = (const float*)d_in[3];
    const float* a1_dst = (const float*)d_in[4];
    const float* b1     = (const float*)d_in[5];
    const float* W2     = (const float*)d_in[6];
    const float* a2_src = (const float*)d_in[7];
    const float* a2_dst = (const float*)d_in[8];
    const float* b2     = (const float*)d_in[9];
    const float* W3     = (const float*)d_in[10];
    const float* a3_src = (const float*)d_in[11];
    const float* a3_dst = (const float*)d_in[12];
    const float* b3     = (const float*)d_in[13];
    float* outp = (float*)d_out;

    const int N = N_NODES, E = N_EDGES;
    const int* src = ei;
    const int* dst = ei + E;

    // ---- workspace layout (bytes) ----
    char* ws = (char*)d_ws;
    size_t off = 0;
    auto alloc = [&](size_t bytes) {
        void* p = ws + off;
        off = (off + bytes + 255) & ~(size_t)255;
        return p;
    };
    int*   rowptr = (int*)alloc((N + 1) * sizeof(int));
    int*   cursor = (int*)alloc(N * sizeof(int));
    int*   col    = (int*)alloc(E * sizeof(int));
    float* s_src  = (float*)alloc((size_t)N * HEADS * sizeof(float));
    float* s_dst  = (float*)alloc((size_t)N * HEADS * sizeof(float));
    float* hA     = (float*)alloc((size_t)N * 256 * sizeof(float));
    float* hB     = (float*)alloc((size_t)N * 256 * sizeof(float));
    float* h3     = (float*)alloc((size_t)N * 16 * sizeof(float));
    (void)ws_size;

    // ---- CSR build (by dst) ----
    hipMemsetAsync(cursor, 0, N * sizeof(int), stream);
    k_hist<<<(E + 255) / 256, 256, 0, stream>>>(dst, cursor, E);
    k_scan<<<1, 1024, 0, stream>>>(cursor, rowptr, N);
    hipMemsetAsync(cursor, 0, N * sizeof(int), stream);
    k_scatter<<<(E + 255) / 256, 256, 0, stream>>>(src, dst, rowptr, cursor, col, E);

    const int aggBlocks = (N + 3) / 4;  // 4 waves (nodes) per 256-thread block

    // ---- layer 1: x[ N,128 ] @ W1[128,256] ----
    {
        dim3 g(256 / 64, (N + 63) / 64);
        k_gemm<<<g, 256, 0, stream>>>(x, W1, hA, N, F_IN, 256);
        k_scores<<<aggBlocks, 256, 0, stream>>>(hA, a1_src, a1_dst, s_src, s_dst, N);
        k_aggregate<<<aggBlocks, 256, 0, stream>>>(hA, rowptr, col, s_src, s_dst, b1, hB, N);
    }
    // ---- layer 2: hB[N,256] @ W2[256,256] ----
    {
        dim3 g(256 / 64, (N + 63) / 64);
        k_gemm<<<g, 256, 0, stream>>>(hB, W2, hA, N, 256, 256);
        k_scores<<<aggBlocks, 256, 0, stream>>>(hA, a2_src, a2_dst, s_src, s_dst, N);
        k_aggregate<<<aggBlocks, 256, 0, stream>>>(hA, rowptr, col, s_src, s_dst, b2, hB, N);
    }
    // ---- layer 3: hB[N,256] @ W3[256,16], then agg + log_softmax ----
    {
        k_gemm3<<<(N + 15) / 16, 256, 0, stream>>>(hB, W3, h3, N, 256);
        k_scores3<<<(N + 255) / 256, 256, 0, stream>>>(h3, a3_src, a3_dst, s_src, s_dst, N);
        k_agg3<<<aggBlocks, 256, 0, stream>>>(h3, rowptr, col, s_src, s_dst, b3, outp, N);
    }
}

// Round 2
// 569.434 us; speedup vs baseline: 1.4333x; 1.4333x over previous
//
#include <hip/hip_runtime.h>
#include <hip/hip_bf16.h>
#include <math.h>

#define N_NODES 50000
#define N_EDGES 800000
#define F_IN    128
#define HID     64
#define HEADS   4
#define NCLS    16
#define NEG_SLOPE 0.2f

typedef __attribute__((ext_vector_type(8))) short short8v;
typedef __attribute__((ext_vector_type(4))) float f32x4;

static __device__ __forceinline__ float lrelu(float x) {
    return x >= 0.f ? x : NEG_SLOPE * x;
}
static __device__ __forceinline__ float b2f(unsigned short u) {
    return __uint_as_float(((unsigned)u) << 16);
}
static __device__ __forceinline__ unsigned short f2b(float f) {
    __hip_bfloat16 b = __float2bfloat16(f);
    return *(unsigned short*)&b;
}

// ---------------- converts ----------------
__global__ void k_f2b4(const float* __restrict__ in, unsigned short* __restrict__ out, int n4) {
    int i = blockIdx.x * blockDim.x + threadIdx.x;
    if (i < n4) {
        float4 v = *(const float4*)(in + i * 4);
        ushort4 o = { f2b(v.x), f2b(v.y), f2b(v.z), f2b(v.w) };
        *(ushort4*)(out + i * 4) = o;
    }
}

// Wt[c][k] = W[k][c], bf16
__global__ void k_wt(const float* __restrict__ W, unsigned short* __restrict__ Wt, int K, int N) {
    int i = blockIdx.x * blockDim.x + threadIdx.x;
    if (i < K * N) {
        int k = i / N, c = i % N;
        Wt[c * K + k] = f2b(W[i]);
    }
}

// ---------------- CSR build ----------------
__global__ void k_hist(const int* __restrict__ dst, int* __restrict__ counts, int e) {
    int i = blockIdx.x * blockDim.x + threadIdx.x;
    if (i < e) atomicAdd(&counts[dst[i]], 1);
}

__global__ __launch_bounds__(256) void k_scan1(const int* __restrict__ counts, int* __restrict__ incl,
                                               int* __restrict__ bsums, int n) {
    __shared__ int wsum[4];
    int blk = blockIdx.x, tid = threadIdx.x;
    int lane = tid & 63, w = tid >> 6;
    int i0 = blk * 1024 + tid * 4;
    int v[4];
    #pragma unroll
    for (int j = 0; j < 4; j++) v[j] = (i0 + j < n) ? counts[i0 + j] : 0;
    int t = v[0] + v[1] + v[2] + v[3];
    int x = t;
    #pragma unroll
    for (int d = 1; d < 64; d <<= 1) { int y = __shfl_up(x, d); if (lane >= d) x += y; }
    if (lane == 63) wsum[w] = x;
    __syncthreads();
    int woff = 0;
    #pragma unroll
    for (int ww = 0; ww < 4; ww++) woff += (ww < w) ? wsum[ww] : 0;
    int p = woff + x - t;   // exclusive prefix for this thread
    #pragma unroll
    for (int j = 0; j < 4; j++) { p += v[j]; if (i0 + j < n) incl[i0 + j] = p; }
    if (tid == 255) bsums[blk] = woff + x;
}

__global__ void k_scan2(const int* __restrict__ bsums, int* __restrict__ boffs, int nb, int* rowptr_end) {
    int lane = threadIdx.x;
    int v = (lane < nb) ? bsums[lane] : 0;
    int x = v;
    #pragma unroll
    for (int d = 1; d < 64; d <<= 1) { int y = __shfl_up(x, d); if (lane >= d) x += y; }
    if (lane < nb) boffs[lane] = x - v;
    if (lane == 63) *rowptr_end = x;
}

__global__ void k_scan3(const int* __restrict__ incl, const int* __restrict__ counts,
                        const int* __restrict__ boffs, int* __restrict__ rowptr, int n) {
    int i = blockIdx.x * blockDim.x + threadIdx.x;
    if (i < n) rowptr[i] = boffs[i >> 10] + incl[i] - counts[i];
}

__global__ void k_scatter(const int* __restrict__ src, const int* __restrict__ dst,
                          const int* __restrict__ rowptr, int* __restrict__ cursor,
                          int* __restrict__ col, int e) {
    int i = blockIdx.x * blockDim.x + threadIdx.x;
    if (i < e) {
        int d = dst[i];
        int pos = rowptr[d] + atomicAdd(&cursor[d], 1);
        col[pos] = src[i];
    }
}

// ---------------- MFMA GEMM: C[M,256] = A[M,K] @ Bt[256,K]^T  (bf16 in, bf16 out) ----
// 128x128 tile, 4 waves (2x2), each wave 64x64 via 4x4 frags of 16x16x32.
// LDS swizzle: phys chunk within 8-row group = lc ^ (r&3) ^ ((r>>2)&1)  (2-way banks)
static __device__ __forceinline__ int swz(int r, int lc) {
    return r * 4 + (lc ^ (r & 3) ^ ((r >> 2) & 1));
}

__global__ __launch_bounds__(256) void k_gemm_mfma(const unsigned short* __restrict__ A,
                                                   const unsigned short* __restrict__ Bt,
                                                   unsigned short* __restrict__ C,
                                                   int M, int K) {
    const int N = 256;
    __shared__ unsigned short Asm[128 * 32];
    __shared__ unsigned short Bsm[128 * 32];
    int tid = threadIdx.x;
    int lane = tid & 63, wid = tid >> 6;
    int bx = blockIdx.x & 1, by = blockIdx.x >> 1;
    int row0 = by * 128, col0 = bx * 128;
    int wr = wid >> 1, wc = wid & 1;
    f32x4 acc[4][4] = {};

    for (int k0 = 0; k0 < K; k0 += 32) {
        __syncthreads();
        #pragma unroll
        for (int s = 0; s < 2; s++) {
            int c = tid + s * 256;
            int row = c >> 2, lc = c & 3;
            int gr = row0 + row; if (gr >= M) gr = 0;
            uint4 va = *(const uint4*)(A + (size_t)gr * K + k0 + lc * 8);
            *(uint4*)(&Asm[swz(row, lc) * 8]) = va;
            uint4 vb = *(const uint4*)(Bt + (size_t)(col0 + row) * K + k0 + lc * 8);
            *(uint4*)(&Bsm[swz(row, lc) * 8]) = vb;
        }
        __syncthreads();
        short8v af[4], bf[4];
        int lq = lane >> 4;
        #pragma unroll
        for (int m = 0; m < 4; m++) {
            int r = wr * 64 + m * 16 + (lane & 15);
            af[m] = *(const short8v*)(&Asm[swz(r, lq) * 8]);
        }
        #pragma unroll
        for (int n = 0; n < 4; n++) {
            int r = wc * 64 + n * 16 + (lane & 15);
            bf[n] = *(const short8v*)(&Bsm[swz(r, lq) * 8]);
        }
        #pragma unroll
        for (int m = 0; m < 4; m++)
            #pragma unroll
            for (int n = 0; n < 4; n++)
                acc[m][n] = __builtin_amdgcn_mfma_f32_16x16x32_bf16(af[m], bf[n], acc[m][n], 0, 0, 0);
    }

    #pragma unroll
    for (int m = 0; m < 4; m++) {
        #pragma unroll
        for (int r = 0; r < 4; r++) {
            int row = row0 + wr * 64 + m * 16 + (lane >> 4) * 4 + r;
            if (row < M) {
                #pragma unroll
                for (int n = 0; n < 4; n++) {
                    C[(size_t)row * N + col0 + wc * 64 + n * 16 + (lane & 15)] = f2b(acc[m][n][r]);
                }
            }
        }
    }
}

// ---------------- attention scores, layers 1&2 (H=4, D=64), bf16 h ----------------
__global__ void k_scores(const unsigned short* __restrict__ h, const float* __restrict__ a_src,
                         const float* __restrict__ a_dst, float* __restrict__ s_src,
                         float* __restrict__ s_dst, int n) {
    int wave = (blockIdx.x * blockDim.x + threadIdx.x) >> 6;
    int lane = threadIdx.x & 63;
    if (wave >= n) return;
    ushort4 hv  = *(const ushort4*)(h + (size_t)wave * 256 + lane * 4);
    float4 av1 = *(const float4*)(a_src + lane * 4);
    float4 av2 = *(const float4*)(a_dst + lane * 4);
    float h0 = b2f(hv.x), h1 = b2f(hv.y), h2 = b2f(hv.z), h3 = b2f(hv.w);
    float ps = h0 * av1.x + h1 * av1.y + h2 * av1.z + h3 * av1.w;
    float pd = h0 * av2.x + h1 * av2.y + h2 * av2.z + h3 * av2.w;
    #pragma unroll
    for (int off = 1; off < 16; off <<= 1) {
        ps += __shfl_xor(ps, off);
        pd += __shfl_xor(pd, off);
    }
    if ((lane & 15) == 0) {
        int head = lane >> 4;
        s_src[wave * 4 + head] = ps;
        s_dst[wave * 4 + head] = pd;
    }
}

// ---------------- fused segment-softmax + aggregation, layers 1&2 (bf16 h in/out) ----
__global__ void k_aggregate(const unsigned short* __restrict__ h, const int* __restrict__ rowptr,
                            const int* __restrict__ col, const float* __restrict__ s_src,
                            const float* __restrict__ s_dst, const float* __restrict__ bias,
                            unsigned short* __restrict__ out, int n) {
    int wave = (blockIdx.x * blockDim.x + threadIdx.x) >> 6;
    int lane = threadIdx.x & 63;
    if (wave >= n) return;
    int head = lane >> 4;
    int f0 = lane * 4;
    float sd = s_dst[wave * 4 + head];
    float sc_self = lrelu(s_src[wave * 4 + head] + sd);
    int rs = rowptr[wave], re = rowptr[wave + 1];
    float m = sc_self;
    for (int i = rs; i < re; i++) {
        float sc = lrelu(s_src[col[i] * 4 + head] + sd);
        m = fmaxf(m, sc);
    }
    float z = 0.f;
    float a0 = 0.f, a1 = 0.f, a2 = 0.f, a3 = 0.f;
    {
        float p = __expf(sc_self - m);
        z += p;
        ushort4 hv = *(const ushort4*)(h + (size_t)wave * 256 + f0);
        a0 += p * b2f(hv.x); a1 += p * b2f(hv.y); a2 += p * b2f(hv.z); a3 += p * b2f(hv.w);
    }
    for (int i = rs; i < re; i++) {
        int s = col[i];
        float sc = lrelu(s_src[s * 4 + head] + sd);
        float p = __expf(sc - m);
        z += p;
        ushort4 hv = *(const ushort4*)(h + (size_t)s * 256 + f0);
        a0 += p * b2f(hv.x); a1 += p * b2f(hv.y); a2 += p * b2f(hv.z); a3 += p * b2f(hv.w);
    }
    float inv = 1.f / z;
    float4 bv = *(const float4*)(bias + f0);
    float o0 = a0 * inv + bv.x;
    float o1 = a1 * inv + bv.y;
    float o2 = a2 * inv + bv.z;
    float o3 = a3 * inv + bv.w;
    o0 = o0 > 0.f ? o0 : expm1f(o0);
    o1 = o1 > 0.f ? o1 : expm1f(o1);
    o2 = o2 > 0.f ? o2 : expm1f(o2);
    o3 = o3 > 0.f ? o3 : expm1f(o3);
    ushort4 ov = { f2b(o0), f2b(o1), f2b(o2), f2b(o3) };
    *(ushort4*)(out + (size_t)wave * 256 + f0) = ov;
}

// ---------------- layer 3: GEMM [M,256](bf16) @ [256,16](f32) -> f32 ----------------
__global__ __launch_bounds__(256) void k_gemm3(const unsigned short* __restrict__ A,
                                               const float* __restrict__ B,
                                               float* __restrict__ C, int M, int K) {
    __shared__ float Bs[256 * 16];
    for (int i = threadIdx.x; i < K * 16; i += 256) Bs[i] = B[i];
    __syncthreads();
    int tx = threadIdx.x & 15;
    int ty = threadIdx.x >> 4;
    int row = blockIdx.x * 16 + ty;
    if (row >= M) return;
    const unsigned short* Ar = A + (size_t)row * K;
    float acc = 0.f;
    for (int kk = 0; kk < K; kk += 8) {
        uint4 va = *(const uint4*)(Ar + kk);
        const unsigned* u = (const unsigned*)&va;
        #pragma unroll
        for (int j = 0; j < 4; j++) {
            float lo = __uint_as_float(u[j] << 16);
            float hi = __uint_as_float(u[j] & 0xffff0000u);
            acc += lo * Bs[(kk + 2 * j) * 16 + tx] + hi * Bs[(kk + 2 * j + 1) * 16 + tx];
        }
    }
    C[(size_t)row * 16 + tx] = acc;
}

// ---------------- layer 3 scores (H=1, D=16) ----------------
__global__ void k_scores3(const float* __restrict__ h3, const float* __restrict__ a_src,
                          const float* __restrict__ a_dst, float* __restrict__ s_src,
                          float* __restrict__ s_dst, int n) {
    int i = blockIdx.x * blockDim.x + threadIdx.x;
    if (i >= n) return;
    float ps = 0.f, pd = 0.f;
    #pragma unroll
    for (int c = 0; c < 16; c++) {
        float v = h3[(size_t)i * 16 + c];
        ps += v * a_src[c];
        pd += v * a_dst[c];
    }
    s_src[i] = ps;
    s_dst[i] = pd;
}

// ---------------- layer 3 aggregation + bias + log_softmax ----------------
__global__ void k_agg3(const float* __restrict__ h3, const int* __restrict__ rowptr,
                       const int* __restrict__ col, const float* __restrict__ s_src,
                       const float* __restrict__ s_dst, const float* __restrict__ b3,
                       float* __restrict__ outp, int n) {
    int wave = (blockIdx.x * blockDim.x + threadIdx.x) >> 6;
    int lane = threadIdx.x & 63;
    if (wave >= n) return;
    float sd = s_dst[wave];
    float sc_self = lrelu(s_src[wave] + sd);
    int rs = rowptr[wave], re = rowptr[wave + 1];
    float m = sc_self;
    for (int i = rs; i < re; i++) m = fmaxf(m, lrelu(s_src[col[i]] + sd));
    float z = 0.f, acc = 0.f;
    {
        float p = __expf(sc_self - m);
        z += p;
        if (lane < 16) acc += p * h3[(size_t)wave * 16 + lane];
    }
    for (int i = rs; i < re; i++) {
        int s = col[i];
        float p = __expf(lrelu(s_src[s] + sd) - m);
        z += p;
        if (lane < 16) acc += p * h3[(size_t)s * 16 + lane];
    }
    if (lane < 16) {
        float v = acc / z + b3[lane];
        float mm = v;
        #pragma unroll
        for (int off = 1; off < 16; off <<= 1) mm = fmaxf(mm, __shfl_xor(mm, off));
        float se = __expf(v - mm);
        #pragma unroll
        for (int off = 1; off < 16; off <<= 1) se += __shfl_xor(se, off);
        outp[(size_t)wave * 16 + lane] = v - mm - logf(se);
    }
}

extern "C" void kernel_launch(void* const* d_in, const int* in_sizes, int n_in,
                              void* d_out, int out_size, void* d_ws, size_t ws_size,
                              hipStream_t stream) {
    const float* x      = (const float*)d_in[0];
    const int*   ei     = (const int*)d_in[1];
    const float* W1     = (const float*)d_in[2];
    const float* a1_src = (const float*)d_in[3];
    const float* a1_dst = (const float*)d_in[4];
    const float* b1     = (const float*)d_in[5];
    const float* W2     = (const float*)d_in[6];
    const float* a2_src = (const float*)d_in[7];
    const float* a2_dst = (const float*)d_in[8];
    const float* b2     = (const float*)d_in[9];
    const float* W3     = (const float*)d_in[10];
    const float* a3_src = (const float*)d_in[11];
    const float* a3_dst = (const float*)d_in[12];
    const float* b3     = (const float*)d_in[13];
    float* outp = (float*)d_out;

    const int N = N_NODES, E = N_EDGES;
    const int* src = ei;
    const int* dst = ei + E;

    char* ws = (char*)d_ws;
    size_t off = 0;
    auto alloc = [&](size_t bytes) {
        void* p = ws + off;
        off = (off + bytes + 255) & ~(size_t)255;
        return p;
    };
    int*   rowptr = (int*)alloc((N + 1) * sizeof(int));
    int*   counts = (int*)alloc(N * sizeof(int));      // reused as cursor
    int*   col    = (int*)alloc(E * sizeof(int));
    int*   incl   = (int*)alloc(N * sizeof(int));
    int*   bsums  = (int*)alloc(64 * sizeof(int));
    int*   boffs  = (int*)alloc(64 * sizeof(int));
    float* s_src  = (float*)alloc((size_t)N * HEADS * sizeof(float));
    float* s_dst  = (float*)alloc((size_t)N * HEADS * sizeof(float));
    unsigned short* xb  = (unsigned short*)alloc((size_t)N * F_IN * sizeof(short));
    unsigned short* W1t = (unsigned short*)alloc((size_t)256 * F_IN * sizeof(short));
    unsigned short* W2t = (unsigned short*)alloc((size_t)256 * 256 * sizeof(short));
    unsigned short* hA  = (unsigned short*)alloc((size_t)N * 256 * sizeof(short));
    unsigned short* hB  = (unsigned short*)alloc((size_t)N * 256 * sizeof(short));
    float* h3     = (float*)alloc((size_t)N * 16 * sizeof(float));
    (void)ws_size;

    // ---- converts ----
    k_f2b4<<<(N * F_IN / 4 + 255) / 256, 256, 0, stream>>>(x, xb, N * F_IN / 4);
    k_wt<<<(F_IN * 256 + 255) / 256, 256, 0, stream>>>(W1, W1t, F_IN, 256);
    k_wt<<<(256 * 256 + 255) / 256, 256, 0, stream>>>(W2, W2t, 256, 256);

    // ---- CSR build (by dst) ----
    hipMemsetAsync(counts, 0, N * sizeof(int), stream);
    k_hist<<<(E + 255) / 256, 256, 0, stream>>>(dst, counts, E);
    const int nb = (N + 1023) / 1024;
    k_scan1<<<nb, 256, 0, stream>>>(counts, incl, bsums, N);
    k_scan2<<<1, 64, 0, stream>>>(bsums, boffs, nb, rowptr + N);
    k_scan3<<<(N + 255) / 256, 256, 0, stream>>>(incl, counts, boffs, rowptr, N);
    hipMemsetAsync(counts, 0, N * sizeof(int), stream);
    k_scatter<<<(E + 255) / 256, 256, 0, stream>>>(src, dst, rowptr, counts, col, E);

    const int aggBlocks = (N + 3) / 4;
    const int gemmBlocks = ((N + 127) / 128) * 2;

    // ---- layer 1 ----
    k_gemm_mfma<<<gemmBlocks, 256, 0, stream>>>(xb, W1t, hA, N, F_IN);
    k_scores<<<aggBlocks, 256, 0, stream>>>(hA, a1_src, a1_dst, s_src, s_dst, N);
    k_aggregate<<<aggBlocks, 256, 0, stream>>>(hA, rowptr, col, s_src, s_dst, b1, hB, N);
    // ---- layer 2 ----
    k_gemm_mfma<<<gemmBlocks, 256, 0, stream>>>(hB, W2t, hA, N, 256);
    k_scores<<<aggBlocks, 256, 0, stream>>>(hA, a2_src, a2_dst, s_src, s_dst, N);
    k_aggregate<<<aggBlocks, 256, 0, stream>>>(hA, rowptr, col, s_src, s_dst, b2, hB, N);
    // ---- layer 3 ----
    k_gemm3<<<(N + 15) / 16, 256, 0, stream>>>(hB, W3, h3, N, 256);
    k_scores3<<<(N + 255) / 256, 256, 0, stream>>>(h3, a3_src, a3_dst, s_src, s_dst, N);
    k_agg3<<<aggBlocks, 256, 0, stream>>>(h3, rowptr, col, s_src, s_dst, b3, outp, N);
}